// Round 2
// baseline (3135.856 us; speedup 1.0000x reference)
//
#include <hip/hip_runtime.h>
#include <cstdint>

#define TT 512
#define BB 128
#define DD 512
#define HH 512
#define KTOT 1024
#define LDK 1032   // padded K stride in LDS (bf16 elements), 16B-aligned rows

typedef short bf16x8 __attribute__((ext_vector_type(8)));
typedef float f32x4 __attribute__((ext_vector_type(4)));

__device__ inline unsigned short f2bfs(float f) {
    unsigned int u = __builtin_bit_cast(unsigned int, f);
    u = (u + 0x7FFFu + ((u >> 16) & 1u)) >> 16;
    return (unsigned short)u;
}

__device__ inline float sigf(float x) { return 1.f / (1.f + __expf(-x)); }
__device__ inline float tanhfast(float x) { return 2.f * sigf(2.f * x) - 1.f; }

__device__ inline bf16x8 load8w(const float* p) {
    const float4* p4 = (const float4*)p;
    float4 a = p4[0], b = p4[1];
    bf16x8 r;
    r[0] = (short)f2bfs(a.x); r[1] = (short)f2bfs(a.y);
    r[2] = (short)f2bfs(a.z); r[3] = (short)f2bfs(a.w);
    r[4] = (short)f2bfs(b.x); r[5] = (short)f2bfs(b.y);
    r[6] = (short)f2bfs(b.z); r[7] = (short)f2bfs(b.w);
    return r;
}

// h exchange: hbuf is u32 per element: (tag16 << 16) | bf16(h).
// tag = t+1 (1..512, never 0). A word is valid for step t+1 iff tag == t+1.
// Single-word atomicity makes data+readiness indivisible -> no fences, no flags.
// Ping-pong slots: producer of h_t writes slot t&1. All-to-all dependency
// within a row-group bounds producer/consumer skew to 1 step, so a producer
// cannot overwrite a tag before every consumer in the group validated it
// (its next write to the same slot requires this consumer's stores, which
// happen only after this consumer's validation + __syncthreads()).
// Workspace MUST be zeroed per launch (stale tags from a prior run can match).
__global__ __launch_bounds__(256, 1) void qlstm_kernel(
    const float* __restrict__ X,
    const float* __restrict__ Wf, const float* __restrict__ bfb,
    const float* __restrict__ Wi, const float* __restrict__ bi,
    const float* __restrict__ Wu, const float* __restrict__ bu,
    const float* __restrict__ Wo, const float* __restrict__ bo,
    const float* __restrict__ Ws1, const float* __restrict__ bs1,
    const float* __restrict__ Ws2, const float* __restrict__ bs2,
    float* __restrict__ out,
    unsigned int* __restrict__ hbuf)   // [2][BB][HH] tagged u32 ping-pong
{
    const int tid  = threadIdx.x;
    const int bid  = blockIdx.x;
    // XCD-local pipelines (speed heuristic; correctness is per-access agent-scope).
    const int rg   = bid & 7;
    const int cg   = bid >> 3;
    const int b0   = rg * 16;
    const int lane = tid & 63;
    const int wv   = tid >> 6;    // wave -> gate {0:i, 1:u, 2:o, 3:f-head}
    const int qd   = lane >> 4;
    const int nn   = lane & 15;

    __shared__ unsigned short comb[16][LDK];   // staged [x|h] rows, bf16
    __shared__ float pc[4][16][17];            // [gate][m][n], padded

    // ---- one-time: this wave's gate weights, full K, as B-fragments ----
    bf16x8 wfr[32];
    {
        bf16x8 z8;
        #pragma unroll
        for (int j = 0; j < 8; ++j) z8[j] = 0;
        const float* Wg = (wv == 0) ? Wi : (wv == 1) ? Wu : (wv == 2) ? Wo : Wf;
        const size_t row = (wv == 3) ? (size_t)nn : (size_t)(cg * 16 + nn);
        const bool valid = (wv < 3) || (nn < 2);
        #pragma unroll
        for (int kk = 0; kk < 32; ++kk)
            wfr[kk] = valid ? load8w(Wg + row * KTOT + kk * 32 + qd * 8) : z8;
    }

    // ---- one-time: small params (f-head computed redundantly per-thread) ----
    const int fm = tid >> 4, fn = tid & 15;
    const int gcol = cg * 16 + fn;
    const float bir = bi[gcol], bur = bu[gcol], bor = bo[gcol];
    const float bfr0 = bfb[0], bfr1 = bfb[1];
    float ws1r[8], bs1r[4], ws2r[8];
    #pragma unroll
    for (int j = 0; j < 8; ++j) ws1r[j] = Ws1[j];
    #pragma unroll
    for (int j = 0; j < 4; ++j) bs1r[j] = bs1[j];
    #pragma unroll
    for (int j = 0; j < 8; ++j) ws2r[j] = Ws2[j];
    const float bs2r0 = bs2[0], bs2r1 = bs2[1];

    // ---- prologue: stage X(0) into comb; zero h-half (h_{-1} = 0) ----
    {
        const float4* xs = (const float4*)(X + (size_t)b0 * DD);
        #pragma unroll
        for (int i = 0; i < 8; ++i) {
            const int v = tid + i * 256;
            float4 f4 = xs[v];
            const int row = v >> 7, col = (v & 127) << 2;
            unsigned short* d = &comb[row][col];
            d[0] = f2bfs(f4.x); d[1] = f2bfs(f4.y);
            d[2] = f2bfs(f4.z); d[3] = f2bfs(f4.w);
        }
        #pragma unroll
        for (int i = 0; i < 16; ++i) {
            const int v = tid + i * 256;           // u32 units over h-half
            const int row = v >> 8, c2 = (v & 255) << 1;
            *(unsigned int*)&comb[row][DD + c2] = 0u;
        }
    }

    float cval = 0.f;                  // persistent cell state for (fm, fn)
    unsigned long long w[16];          // in-flight tagged h words (2 per u64)
    unsigned int pend = 0;             // bitmask of w[] not yet validated

    for (int t = 0; t < TT; ++t) {
        __syncthreads();   // (a0) x-half staged (prev shadow), pc reads done

        // ---- x-part MFMAs (K = 0..511) — overlaps in-flight h sweep ----
        f32x4 ac0 = {0.f, 0.f, 0.f, 0.f}, ac1 = ac0;
        #pragma unroll
        for (int kk = 0; kk < 16; kk += 2) {
            bf16x8 av0 = *(const bf16x8*)&comb[nn][kk * 32 + qd * 8];
            bf16x8 av1 = *(const bf16x8*)&comb[nn][(kk + 1) * 32 + qd * 8];
            ac0 = __builtin_amdgcn_mfma_f32_16x16x32_bf16(av0, wfr[kk], ac0, 0, 0, 0);
            ac1 = __builtin_amdgcn_mfma_f32_16x16x32_bf16(av1, wfr[kk + 1], ac1, 0, 0, 0);
        }

        // ---- finish pre-issued h_{t-1} sweep; write validated words to LDS ----
        if (pend) {
            const unsigned long long pat =
                ((unsigned long long)(unsigned int)t << 16) |
                ((unsigned long long)(unsigned int)t << 48);
            const unsigned long long* hs = (const unsigned long long*)(hbuf
                + (size_t)((t + 1) & 1) * BB * HH + (size_t)b0 * HH);
            while (pend) {
                unsigned int np = 0;
                #pragma unroll
                for (int i = 0; i < 16; ++i) if (pend & (1u << i)) {
                    const unsigned long long ww = w[i];
                    if ((ww & 0xFFFF0000FFFF0000ull) == pat) {
                        const int v = tid + i * 256;
                        const int row = v >> 8, c2 = (v & 255) << 1;
                        *(unsigned int*)&comb[row][DD + c2] =
                            (unsigned int)(ww & 0xFFFFu)
                          | (((unsigned int)(ww >> 32) & 0xFFFFu) << 16);
                    } else np |= (1u << i);
                }
                pend = np;
                if (np) {
                    __builtin_amdgcn_s_sleep(1);
                    #pragma unroll
                    for (int i = 0; i < 16; ++i) if (np & (1u << i))
                        w[i] = __hip_atomic_load(&hs[tid + i * 256],
                                 __ATOMIC_RELAXED, __HIP_MEMORY_SCOPE_AGENT);
                }
            }
        }
        __syncthreads();   // (a1) h-half of comb ready

        // ---- h-part MFMAs (K = 512..1023) — the only MFMAs after h lands ----
        #pragma unroll
        for (int kk = 16; kk < 32; kk += 2) {
            bf16x8 av0 = *(const bf16x8*)&comb[nn][kk * 32 + qd * 8];
            bf16x8 av1 = *(const bf16x8*)&comb[nn][(kk + 1) * 32 + qd * 8];
            ac0 = __builtin_amdgcn_mfma_f32_16x16x32_bf16(av0, wfr[kk], ac0, 0, 0, 0);
            ac1 = __builtin_amdgcn_mfma_f32_16x16x32_bf16(av1, wfr[kk + 1], ac1, 0, 0, 0);
        }
        #pragma unroll
        for (int r = 0; r < 4; ++r)
            pc[wv][qd * 4 + r][nn] = ac0[r] + ac1[r];
        __syncthreads();   // (b) pc ready, comb reads done

        // ---- f-head MLP+softmax (redundant per-thread) + gate update ----
        const float l0 = bfr0 + pc[3][fm][0];
        const float l1 = bfr1 + pc[3][fm][1];
        const float hd0 = tanhfast(ws1r[0] * l0 + ws1r[1] * l1 + bs1r[0]);
        const float hd1 = tanhfast(ws1r[2] * l0 + ws1r[3] * l1 + bs1r[1]);
        const float hd2 = tanhfast(ws1r[4] * l0 + ws1r[5] * l1 + bs1r[2]);
        const float hd3 = tanhfast(ws1r[6] * l0 + ws1r[7] * l1 + bs1r[3]);
        const float s0 = bs2r0 + ws2r[0]*hd0 + ws2r[1]*hd1 + ws2r[2]*hd2 + ws2r[3]*hd3;
        const float s1 = bs2r1 + ws2r[4]*hd0 + ws2r[5]*hd1 + ws2r[6]*hd2 + ws2r[7]*hd3;
        const float fval = sigf(s0 - s1);

        const float iv = sigf(bir + pc[0][fm][fn]);
        const float gv = tanhfast(bur + pc[1][fm][fn]);
        const float ov = sigf(bor + pc[2][fm][fn]);
        cval = fval * cval + iv * gv;
        const float hv = ov * tanhfast(cval);
        const int b = b0 + fm;

        // ---- tagged h store: data+readiness in one atomic word, no fence ----
        {
            unsigned int hw = ((unsigned int)(t + 1) << 16)
                            | (unsigned int)f2bfs(hv);
            __hip_atomic_store(
                hbuf + (size_t)(t & 1) * BB * HH + (size_t)b * HH + gcol,
                hw, __ATOMIC_RELAXED, __HIP_MEMORY_SCOPE_AGENT);
        }

        // ---- pre-issue next step's h sweep; latency hides under shadow work ----
        if (t + 1 < TT) {
            const unsigned long long* hs = (const unsigned long long*)(hbuf
                + (size_t)(t & 1) * BB * HH + (size_t)b0 * HH);
            #pragma unroll
            for (int i = 0; i < 16; ++i)
                w[i] = __hip_atomic_load(&hs[tid + i * 256],
                         __ATOMIC_RELAXED, __HIP_MEMORY_SCOPE_AGENT);
            pend = 0xFFFFu;
        }

        // ---- shadow work, fully off the signal path ----
        out[((size_t)t * BB + b) * HH + gcol] = hv;
        if (t == TT - 1) {
            out[(size_t)TT * BB * HH + (size_t)b * HH + gcol] = hv;
            out[(size_t)TT * BB * HH + (size_t)BB * HH + (size_t)b * HH + gcol] = cval;
        }
        {
            const int tn = (t + 1 < TT) ? t + 1 : t;
            const float4* xs = (const float4*)(X + ((size_t)tn * BB + b0) * DD);
            float4 xp[8];
            #pragma unroll
            for (int i = 0; i < 8; ++i) xp[i] = xs[tid + i * 256];
            #pragma unroll
            for (int i = 0; i < 8; ++i) {
                const int v = tid + i * 256;
                const int row = v >> 7, col = (v & 127) << 2;
                unsigned short* d = &comb[row][col];
                d[0] = f2bfs(xp[i].x); d[1] = f2bfs(xp[i].y);
                d[2] = f2bfs(xp[i].z); d[3] = f2bfs(xp[i].w);
            }
        }
    }
}

extern "C" void kernel_launch(void* const* d_in, const int* in_sizes, int n_in,
                              void* d_out, int out_size, void* d_ws, size_t ws_size,
                              hipStream_t stream) {
    const float* X   = (const float*)d_in[0];
    const float* Wf  = (const float*)d_in[1];
    const float* bfb = (const float*)d_in[2];
    const float* Wi  = (const float*)d_in[3];
    const float* bi  = (const float*)d_in[4];
    const float* Wu  = (const float*)d_in[5];
    const float* bu  = (const float*)d_in[6];
    const float* Wo  = (const float*)d_in[7];
    const float* bo  = (const float*)d_in[8];
    const float* Ws1 = (const float*)d_in[9];
    const float* bs1 = (const float*)d_in[10];
    const float* Ws2 = (const float*)d_in[11];
    const float* bs2 = (const float*)d_in[12];
    float* out = (float*)d_out;

    // hbuf: [2][BB][HH] tagged u32 = 512 KB. Zeroing is REQUIRED: stale tags
    // from a prior launch could spuriously match (tags repeat 1..512 per run).
    unsigned int* hbuf = (unsigned int*)d_ws;
    hipMemsetAsync(d_ws, 0, (size_t)2 * BB * HH * sizeof(unsigned int), stream);
    qlstm_kernel<<<dim3(256), dim3(256), 0, stream>>>(
        X, Wf, bfb, Wi, bi, Wu, bu, Wo, bo, Ws1, bs1, Ws2, bs2, out, hbuf);
}

// Round 3
// 2439.292 us; speedup vs baseline: 1.2856x; 1.2856x over previous
//
#include <hip/hip_runtime.h>
#include <cstdint>

#define TT 512
#define BB 128
#define DD 512
#define HH 512
#define KTOT 1024
#define LDK 1032   // padded K stride in LDS (bf16 elements), 16B-aligned rows

typedef short bf16x8 __attribute__((ext_vector_type(8)));
typedef float f32x4 __attribute__((ext_vector_type(4)));

__device__ inline unsigned short f2bfs(float f) {
    unsigned int u = __builtin_bit_cast(unsigned int, f);
    u = (u + 0x7FFFu + ((u >> 16) & 1u)) >> 16;
    return (unsigned short)u;
}

__device__ inline float sigf(float x) { return 1.f / (1.f + __expf(-x)); }
__device__ inline float tanhfast(float x) { return 2.f * sigf(2.f * x) - 1.f; }

__device__ inline bf16x8 load8w(const float* p) {
    const float4* p4 = (const float4*)p;
    float4 a = p4[0], b = p4[1];
    bf16x8 r;
    r[0] = (short)f2bfs(a.x); r[1] = (short)f2bfs(a.y);
    r[2] = (short)f2bfs(a.z); r[3] = (short)f2bfs(a.w);
    r[4] = (short)f2bfs(b.x); r[5] = (short)f2bfs(b.y);
    r[6] = (short)f2bfs(b.z); r[7] = (short)f2bfs(b.w);
    return r;
}

// Exchange design (post-mortem of tagged-word regression, r2):
//  - detect via per-(t,rg) flag lines: 128 u32 words, one per producer WAVE.
//    Producer wave: h-stores -> s_waitcnt vmcnt(0) (per-wave drain, no WG
//    barrier) -> 1 flag store. Flags are per-t (never reused) so no tags.
//  - consumer: pre-issues one flag load before the x-part MFMAs (latency
//    hides under them), then polls; after pass, ONE bf16 data sweep.
//  - gate GEMM split: x-part (K=0..511) before the wait, h-part after.
__global__ __launch_bounds__(256, 1) void qlstm_kernel(
    const float* __restrict__ X,
    const float* __restrict__ Wf, const float* __restrict__ bfb,
    const float* __restrict__ Wi, const float* __restrict__ bi,
    const float* __restrict__ Wu, const float* __restrict__ bu,
    const float* __restrict__ Wo, const float* __restrict__ bo,
    const float* __restrict__ Ws1, const float* __restrict__ bs1,
    const float* __restrict__ Ws2, const float* __restrict__ bs2,
    float* __restrict__ out,
    unsigned int* __restrict__ flags,    // [TT][8][128]: one word per producer wave
    unsigned short* __restrict__ hbuf)   // [2][BB][HH] bf16 ping-pong
{
    const int tid  = threadIdx.x;
    const int bid  = blockIdx.x;
    // XCD-local pipelines (speed heuristic; correctness is per-access agent-scope).
    const int rg   = bid & 7;
    const int cg   = bid >> 3;
    const int b0   = rg * 16;
    const int lane = tid & 63;
    const int wv   = tid >> 6;    // wave -> gate {0:i, 1:u, 2:o, 3:f-head}
    const int qd   = lane >> 4;
    const int nn   = lane & 15;

    __shared__ unsigned short comb[16][LDK];   // staged [x|h] rows, bf16
    __shared__ float pc[4][16][17];            // [gate][m][n], padded

    // ---- one-time: this wave's gate weights, full K, as B-fragments ----
    bf16x8 wfr[32];
    {
        bf16x8 z8;
        #pragma unroll
        for (int j = 0; j < 8; ++j) z8[j] = 0;
        const float* Wg = (wv == 0) ? Wi : (wv == 1) ? Wu : (wv == 2) ? Wo : Wf;
        const size_t row = (wv == 3) ? (size_t)nn : (size_t)(cg * 16 + nn);
        const bool valid = (wv < 3) || (nn < 2);
        #pragma unroll
        for (int kk = 0; kk < 32; ++kk)
            wfr[kk] = valid ? load8w(Wg + row * KTOT + kk * 32 + qd * 8) : z8;
    }

    // ---- one-time: small params (f-head computed redundantly per-thread) ----
    const int fm = tid >> 4, fn = tid & 15;
    const int gcol = cg * 16 + fn;
    const float bir = bi[gcol], bur = bu[gcol], bor = bo[gcol];
    const float bfr0 = bfb[0], bfr1 = bfb[1];
    float ws1r[8], bs1r[4], ws2r[8];
    #pragma unroll
    for (int j = 0; j < 8; ++j) ws1r[j] = Ws1[j];
    #pragma unroll
    for (int j = 0; j < 4; ++j) bs1r[j] = bs1[j];
    #pragma unroll
    for (int j = 0; j < 8; ++j) ws2r[j] = Ws2[j];
    const float bs2r0 = bs2[0], bs2r1 = bs2[1];

    // ---- prologue: stage X(0) into comb; zero h-half (h_{-1} = 0) ----
    {
        const float4* xs = (const float4*)(X + (size_t)b0 * DD);
        #pragma unroll
        for (int i = 0; i < 8; ++i) {
            const int v = tid + i * 256;
            float4 f4 = xs[v];
            const int row = v >> 7, col = (v & 127) << 2;
            unsigned short* d = &comb[row][col];
            d[0] = f2bfs(f4.x); d[1] = f2bfs(f4.y);
            d[2] = f2bfs(f4.z); d[3] = f2bfs(f4.w);
        }
        #pragma unroll
        for (int i = 0; i < 16; ++i) {
            const int v = tid + i * 256;           // u32 units over h-half
            const int row = v >> 8, c2 = (v & 255) << 1;
            *(unsigned int*)&comb[row][DD + c2] = 0u;
        }
    }

    float cval = 0.f;   // persistent cell state for (fm, fn)

    for (int t = 0; t < TT; ++t) {
        __syncthreads();   // (a0) x-half staged (prev shadow), pc reads done

        // ---- pre-issue one flag-line load; its latency hides under x-MFMAs ----
        const unsigned long long* fl = nullptr;
        unsigned long long fv = ~0ull;
        if (t > 0) {
            fl = (const unsigned long long*)&flags[((t - 1) * 8 + rg) * 128];
            fv = __hip_atomic_load(&fl[lane],
                   __ATOMIC_RELAXED, __HIP_MEMORY_SCOPE_AGENT);
        }

        // ---- x-part MFMAs (K = 0..511) — independent of the recurrence ----
        f32x4 ac0 = {0.f, 0.f, 0.f, 0.f}, ac1 = ac0;
        #pragma unroll
        for (int kk = 0; kk < 16; kk += 2) {
            bf16x8 av0 = *(const bf16x8*)&comb[nn][kk * 32 + qd * 8];
            bf16x8 av1 = *(const bf16x8*)&comb[nn][(kk + 1) * 32 + qd * 8];
            ac0 = __builtin_amdgcn_mfma_f32_16x16x32_bf16(av0, wfr[kk], ac0, 0, 0, 0);
            ac1 = __builtin_amdgcn_mfma_f32_16x16x32_bf16(av1, wfr[kk + 1], ac1, 0, 0, 0);
        }

        // ---- wait for h_{t-1} (cheap flag poll), then ONE data sweep ----
        if (t > 0) {
            while (__ballot(((unsigned int)fv == 0u) |
                            ((unsigned int)(fv >> 32) == 0u)) != 0ull) {
                __builtin_amdgcn_s_sleep(1);
                fv = __hip_atomic_load(&fl[lane],
                       __ATOMIC_RELAXED, __HIP_MEMORY_SCOPE_AGENT);
            }
            asm volatile("" ::: "memory");   // pin sweep after poll
            const unsigned long long* hs = (const unsigned long long*)(hbuf
                + (size_t)((t + 1) & 1) * BB * HH + (size_t)b0 * HH);
            #pragma unroll
            for (int i = 0; i < 8; ++i) {
                unsigned long long u = __hip_atomic_load(&hs[tid + i * 256],
                    __ATOMIC_RELAXED, __HIP_MEMORY_SCOPE_AGENT);
                const int v = tid + i * 256;
                *(unsigned long long*)&comb[v >> 7][DD + ((v & 127) << 2)] = u;
            }
        }
        __syncthreads();   // (a1) h-half of comb ready

        // ---- h-part MFMAs (K = 512..1023) — the only MFMAs after h lands ----
        #pragma unroll
        for (int kk = 16; kk < 32; kk += 2) {
            bf16x8 av0 = *(const bf16x8*)&comb[nn][kk * 32 + qd * 8];
            bf16x8 av1 = *(const bf16x8*)&comb[nn][(kk + 1) * 32 + qd * 8];
            ac0 = __builtin_amdgcn_mfma_f32_16x16x32_bf16(av0, wfr[kk], ac0, 0, 0, 0);
            ac1 = __builtin_amdgcn_mfma_f32_16x16x32_bf16(av1, wfr[kk + 1], ac1, 0, 0, 0);
        }
        #pragma unroll
        for (int r = 0; r < 4; ++r)
            pc[wv][qd * 4 + r][nn] = ac0[r] + ac1[r];
        __syncthreads();   // (b) pc ready, comb reads done

        // ---- f-head MLP+softmax (redundant per-thread) + gate update ----
        const float l0 = bfr0 + pc[3][fm][0];
        const float l1 = bfr1 + pc[3][fm][1];
        const float hd0 = tanhfast(ws1r[0] * l0 + ws1r[1] * l1 + bs1r[0]);
        const float hd1 = tanhfast(ws1r[2] * l0 + ws1r[3] * l1 + bs1r[1]);
        const float hd2 = tanhfast(ws1r[4] * l0 + ws1r[5] * l1 + bs1r[2]);
        const float hd3 = tanhfast(ws1r[6] * l0 + ws1r[7] * l1 + bs1r[3]);
        const float s0 = bs2r0 + ws2r[0]*hd0 + ws2r[1]*hd1 + ws2r[2]*hd2 + ws2r[3]*hd3;
        const float s1 = bs2r1 + ws2r[4]*hd0 + ws2r[5]*hd1 + ws2r[6]*hd2 + ws2r[7]*hd3;
        const float fval = sigf(s0 - s1);

        const float iv = sigf(bir + pc[0][fm][fn]);
        const float gv = tanhfast(bur + pc[1][fm][fn]);
        const float ov = sigf(bor + pc[2][fm][fn]);
        cval = fval * cval + iv * gv;
        const float hv = ov * tanhfast(cval);
        const int b = b0 + fm;

        // ---- paired 32-bit h store (write-through), per-wave drain + flag ----
        {
            unsigned int ub = (unsigned int)f2bfs(hv);
            unsigned int ob = __shfl_xor(ub, 1);
            if ((fn & 1) == 0) {
                unsigned int* hp = (unsigned int*)(hbuf
                    + (size_t)(t & 1) * BB * HH + (size_t)b * HH + gcol);
                __hip_atomic_store(hp, ub | (ob << 16),
                                   __ATOMIC_RELAXED, __HIP_MEMORY_SCOPE_AGENT);
            }
        }
        asm volatile("s_waitcnt vmcnt(0)" ::: "memory");   // per-wave drain only
        if (lane == 0)
            __hip_atomic_store(&flags[(t * 8 + rg) * 128 + cg * 4 + wv], 1u,
                               __ATOMIC_RELAXED, __HIP_MEMORY_SCOPE_AGENT);

        // ---- shadow work, fully off the signal path ----
        out[((size_t)t * BB + b) * HH + gcol] = hv;
        if (t == TT - 1) {
            out[(size_t)TT * BB * HH + (size_t)b * HH + gcol] = hv;
            out[(size_t)TT * BB * HH + (size_t)BB * HH + (size_t)b * HH + gcol] = cval;
        }
        {
            const int tn = (t + 1 < TT) ? t + 1 : t;
            const float4* xs = (const float4*)(X + ((size_t)tn * BB + b0) * DD);
            float4 xp[8];
            #pragma unroll
            for (int i = 0; i < 8; ++i) xp[i] = xs[tid + i * 256];
            #pragma unroll
            for (int i = 0; i < 8; ++i) {
                const int v = tid + i * 256;
                const int row = v >> 7, col = (v & 127) << 2;
                unsigned short* d = &comb[row][col];
                d[0] = f2bfs(xp[i].x); d[1] = f2bfs(xp[i].y);
                d[2] = f2bfs(xp[i].z); d[3] = f2bfs(xp[i].w);
            }
        }
    }
}

extern "C" void kernel_launch(void* const* d_in, const int* in_sizes, int n_in,
                              void* d_out, int out_size, void* d_ws, size_t ws_size,
                              hipStream_t stream) {
    const float* X   = (const float*)d_in[0];
    const float* Wf  = (const float*)d_in[1];
    const float* bfb = (const float*)d_in[2];
    const float* Wi  = (const float*)d_in[3];
    const float* bi  = (const float*)d_in[4];
    const float* Wu  = (const float*)d_in[5];
    const float* bu  = (const float*)d_in[6];
    const float* Wo  = (const float*)d_in[7];
    const float* bo  = (const float*)d_in[8];
    const float* Ws1 = (const float*)d_in[9];
    const float* bs1 = (const float*)d_in[10];
    const float* Ws2 = (const float*)d_in[11];
    const float* bs2 = (const float*)d_in[12];
    float* out = (float*)d_out;

    // flags: [TT][8][128] u32 = 2 MB (per-wave, per-t, never reused);
    // hbuf: [2][BB][HH] bf16 = 256 KB ping-pong.
    unsigned int*   flags = (unsigned int*)d_ws;
    unsigned short* hbuf  = (unsigned short*)((char*)d_ws + (size_t)TT * 8 * 128 * 4);

    hipMemsetAsync(d_ws, 0, (size_t)TT * 8 * 128 * 4, stream);
    qlstm_kernel<<<dim3(256), dim3(256), 0, stream>>>(
        X, Wf, bfb, Wi, bi, Wu, bu, Wo, bo, Ws1, bs1, Ws2, bs2, out, flags, hbuf);
}

// Round 4
// 1980.472 us; speedup vs baseline: 1.5834x; 1.2317x over previous
//
#include <hip/hip_runtime.h>
#include <cstdint>

#define TT 512
#define BB 128
#define DD 512
#define HH 512
#define KTOT 1024

typedef short bf16x8 __attribute__((ext_vector_type(8)));
typedef float f32x4 __attribute__((ext_vector_type(4)));
typedef unsigned long long u64t;

__device__ inline unsigned short f2bfs(float f) {
    unsigned int u = __builtin_bit_cast(unsigned int, f);
    u = (u + 0x7FFFu + ((u >> 16) & 1u)) >> 16;
    return (unsigned short)u;
}

__device__ inline float sigf(float x) { return 1.f / (1.f + __expf(-x)); }
__device__ inline float tanhfast(float x) { return 2.f * sigf(2.f * x) - 1.f; }

__device__ inline bf16x8 load8w(const float* p) {
    const float4* p4 = (const float4*)p;
    float4 a = p4[0], b = p4[1];
    bf16x8 r;
    r[0] = (short)f2bfs(a.x); r[1] = (short)f2bfs(a.y);
    r[2] = (short)f2bfs(a.z); r[3] = (short)f2bfs(a.w);
    r[4] = (short)f2bfs(b.x); r[5] = (short)f2bfs(b.y);
    r[6] = (short)f2bfs(b.z); r[7] = (short)f2bfs(b.w);
    return r;
}

// Symmetric-wave K-split (r4):
//  - wave wv owns K slices {wv*4..wv*4+3} (x) and {16+wv*4..} (h), computing
//    partials for ALL 4 gates over its K=256 slice. x-partials for step t+1
//    are computed in step t's shadow (registers); h fragments are loaded
//    global->register directly (disjoint per wave: no LDS staging barrier).
//  - ONE barrier per step: the pcp partials rendezvous. pcp single-buffer
//    reuse is ordered by the flag dependency: pcp writes for t+1 require
//    observing all flags(t), which are set only after every wave's
//    epilogue-t pcp reads (hv data-depends on them).
//  - flags/h-publish mechanism unchanged from r3 (proven): per-wave flag
//    after s_waitcnt vmcnt(0); consumer pre-issues the flag-line load.
__global__ __launch_bounds__(256, 1) void qlstm_kernel(
    const float* __restrict__ X,
    const float* __restrict__ Wf, const float* __restrict__ bfb,
    const float* __restrict__ Wi, const float* __restrict__ bi,
    const float* __restrict__ Wu, const float* __restrict__ bu,
    const float* __restrict__ Wo, const float* __restrict__ bo,
    const float* __restrict__ Ws1, const float* __restrict__ bs1,
    const float* __restrict__ Ws2, const float* __restrict__ bs2,
    float* __restrict__ out,
    unsigned int* __restrict__ flags,    // [TT][8][128]: one word per producer wave
    unsigned short* __restrict__ hbuf)   // [2][BB][HH] bf16 ping-pong
{
    const int tid  = threadIdx.x;
    const int bid  = blockIdx.x;
    // XCD-local pipelines (speed heuristic; correctness is per-access agent-scope).
    const int rg   = bid & 7;
    const int cg   = bid >> 3;
    const int b0   = rg * 16;
    const int lane = tid & 63;
    const int wv   = tid >> 6;    // wave -> K-slice owner (all 4 gates)
    const int qd   = lane >> 4;
    const int nn   = lane & 15;

    __shared__ float pcp[4][4][16][17];   // [wave][gate][m][n] K-partials, padded

    // ---- one-time: this wave's B-fragments: 4 gates x 8 kk (x:0..3, h:4..7) ----
    bf16x8 wfr[4][8];
    {
        bf16x8 z8;
        #pragma unroll
        for (int j = 0; j < 8; ++j) z8[j] = 0;
        #pragma unroll
        for (int g = 0; g < 4; ++g) {
            const float* Wg = (g == 0) ? Wi : (g == 1) ? Wu : (g == 2) ? Wo : Wf;
            const size_t row = (g == 3) ? (size_t)nn : (size_t)(cg * 16 + nn);
            const bool valid = (g < 3) || (nn < 2);
            #pragma unroll
            for (int j = 0; j < 8; ++j) {
                const int kk = (j < 4) ? (wv * 4 + j) : (16 + wv * 4 + (j - 4));
                wfr[g][j] = valid ? load8w(Wg + row * KTOT + kk * 32 + qd * 8) : z8;
            }
        }
    }

    // ---- one-time: small params (f-head computed redundantly per-thread) ----
    const int fm = tid >> 4, fn = tid & 15;
    const int gcol = cg * 16 + fn;
    const float bir = bi[gcol], bur = bu[gcol], bor = bo[gcol];
    const float bfr0 = bfb[0], bfr1 = bfb[1];
    float ws1r[8], bs1r[4], ws2r[8];
    #pragma unroll
    for (int j = 0; j < 8; ++j) ws1r[j] = Ws1[j];
    #pragma unroll
    for (int j = 0; j < 4; ++j) bs1r[j] = bs1[j];
    #pragma unroll
    for (int j = 0; j < 8; ++j) ws2r[j] = Ws2[j];
    const float bs2r0 = bs2[0], bs2r1 = bs2[1];

    // ---- prologue "shadow": x-partials for step 0 (held in registers) ----
    f32x4 ac[4];
    #pragma unroll
    for (int g = 0; g < 4; ++g) ac[g] = f32x4{0.f, 0.f, 0.f, 0.f};
    {
        bf16x8 xa[4];
        #pragma unroll
        for (int j = 0; j < 4; ++j)
            xa[j] = load8w(X + (size_t)(b0 + nn) * DD + (wv * 4 + j) * 32 + qd * 8);
        #pragma unroll
        for (int j = 0; j < 4; ++j)
            #pragma unroll
            for (int g = 0; g < 4; ++g)
                ac[g] = __builtin_amdgcn_mfma_f32_16x16x32_bf16(xa[j], wfr[g][j], ac[g], 0, 0, 0);
    }

    float cval = 0.f;   // persistent cell state for (fm, fn)
    u64t  fv   = 0;     // pre-issued flag-line word (2 flags)

    for (int t = 0; t < TT; ++t) {
        // ---- live h-part: poll flags(t-1), load own slice direct-to-reg ----
        if (t > 0) {
            const u64t* fl = (const u64t*)&flags[((t - 1) * 8 + rg) * 128];
            while (__ballot(((unsigned int)fv == 0u) |
                            ((unsigned int)(fv >> 32) == 0u)) != 0ull) {
                __builtin_amdgcn_s_sleep(1);
                fv = __hip_atomic_load(&fl[lane],
                       __ATOMIC_RELAXED, __HIP_MEMORY_SCOPE_AGENT);
            }
            asm volatile("" ::: "memory");   // order LDS/loads across poll
            const u64t* hb = (const u64t*)(hbuf + (size_t)((t + 1) & 1) * BB * HH);
            u64t hwv[8];
            #pragma unroll
            for (int j = 0; j < 4; ++j) {
                const u64t* hp = hb + (((b0 + nn) * HH + (wv * 4 + j) * 32 + qd * 8) >> 2);
                hwv[2 * j]     = __hip_atomic_load(hp,
                                   __ATOMIC_RELAXED, __HIP_MEMORY_SCOPE_AGENT);
                hwv[2 * j + 1] = __hip_atomic_load(hp + 1,
                                   __ATOMIC_RELAXED, __HIP_MEMORY_SCOPE_AGENT);
            }
            #pragma unroll
            for (int j = 0; j < 4; ++j) {
                bf16x8 ha;
                ((u64t*)&ha)[0] = hwv[2 * j];
                ((u64t*)&ha)[1] = hwv[2 * j + 1];
                #pragma unroll
                for (int g = 0; g < 4; ++g)
                    ac[g] = __builtin_amdgcn_mfma_f32_16x16x32_bf16(ha, wfr[g][4 + j], ac[g], 0, 0, 0);
            }
        }

        // ---- publish this wave's K-partials; single rendezvous ----
        #pragma unroll
        for (int g = 0; g < 4; ++g)
            #pragma unroll
            for (int r = 0; r < 4; ++r)
                pcp[wv][g][qd * 4 + r][nn] = ac[g][r];
        __syncthreads();   // (b) pcp complete

        // ---- epilogue: sum 4 partials, f-head MLP+softmax, gate update ----
        float s0g = 0.f, s1g = 0.f, s2g = 0.f, sl0 = 0.f, sl1 = 0.f;
        #pragma unroll
        for (int w = 0; w < 4; ++w) {
            s0g += pcp[w][0][fm][fn];
            s1g += pcp[w][1][fm][fn];
            s2g += pcp[w][2][fm][fn];
            sl0 += pcp[w][3][fm][0];
            sl1 += pcp[w][3][fm][1];
        }
        const float l0 = bfr0 + sl0;
        const float l1 = bfr1 + sl1;
        const float hd0 = tanhfast(ws1r[0] * l0 + ws1r[1] * l1 + bs1r[0]);
        const float hd1 = tanhfast(ws1r[2] * l0 + ws1r[3] * l1 + bs1r[1]);
        const float hd2 = tanhfast(ws1r[4] * l0 + ws1r[5] * l1 + bs1r[2]);
        const float hd3 = tanhfast(ws1r[6] * l0 + ws1r[7] * l1 + bs1r[3]);
        const float s0 = bs2r0 + ws2r[0]*hd0 + ws2r[1]*hd1 + ws2r[2]*hd2 + ws2r[3]*hd3;
        const float s1 = bs2r1 + ws2r[4]*hd0 + ws2r[5]*hd1 + ws2r[6]*hd2 + ws2r[7]*hd3;
        const float fval = sigf(s0 - s1);

        const float iv = sigf(bir + s0g);
        const float gv = tanhfast(bur + s1g);
        const float ov = sigf(bor + s2g);
        cval = fval * cval + iv * gv;
        const float hv = ov * tanhfast(cval);
        const int b = b0 + fm;

        // ---- paired 32-bit h store (write-through), per-wave drain + flag ----
        {
            unsigned int ub = (unsigned int)f2bfs(hv);
            unsigned int ob = __shfl_xor(ub, 1);
            if ((fn & 1) == 0) {
                unsigned int* hp = (unsigned int*)(hbuf
                    + (size_t)(t & 1) * BB * HH + (size_t)b * HH + gcol);
                __hip_atomic_store(hp, ub | (ob << 16),
                                   __ATOMIC_RELAXED, __HIP_MEMORY_SCOPE_AGENT);
            }
        }
        asm volatile("s_waitcnt vmcnt(0)" ::: "memory");   // per-wave drain only
        if (lane == 0)
            __hip_atomic_store(&flags[(t * 8 + rg) * 128 + cg * 4 + wv], 1u,
                               __ATOMIC_RELAXED, __HIP_MEMORY_SCOPE_AGENT);

        // ---- shadow: out stores + x-partials for t+1 + flag pre-issue ----
        out[((size_t)t * BB + b) * HH + gcol] = hv;
        if (t == TT - 1) {
            out[(size_t)TT * BB * HH + (size_t)b * HH + gcol] = hv;
            out[(size_t)TT * BB * HH + (size_t)BB * HH + (size_t)b * HH + gcol] = cval;
        }
        if (t + 1 < TT) {
            #pragma unroll
            for (int g = 0; g < 4; ++g) ac[g] = f32x4{0.f, 0.f, 0.f, 0.f};
            bf16x8 xa[4];
            #pragma unroll
            for (int j = 0; j < 4; ++j)
                xa[j] = load8w(X + ((size_t)(t + 1) * BB + b0 + nn) * DD
                               + (wv * 4 + j) * 32 + qd * 8);
            #pragma unroll
            for (int j = 0; j < 4; ++j)
                #pragma unroll
                for (int g = 0; g < 4; ++g)
                    ac[g] = __builtin_amdgcn_mfma_f32_16x16x32_bf16(xa[j], wfr[g][j], ac[g], 0, 0, 0);
            fv = __hip_atomic_load(
                   &((const u64t*)&flags[(t * 8 + rg) * 128])[lane],
                   __ATOMIC_RELAXED, __HIP_MEMORY_SCOPE_AGENT);
        }
    }
}

extern "C" void kernel_launch(void* const* d_in, const int* in_sizes, int n_in,
                              void* d_out, int out_size, void* d_ws, size_t ws_size,
                              hipStream_t stream) {
    const float* X   = (const float*)d_in[0];
    const float* Wf  = (const float*)d_in[1];
    const float* bfb = (const float*)d_in[2];
    const float* Wi  = (const float*)d_in[3];
    const float* bi  = (const float*)d_in[4];
    const float* Wu  = (const float*)d_in[5];
    const float* bu  = (const float*)d_in[6];
    const float* Wo  = (const float*)d_in[7];
    const float* bo  = (const float*)d_in[8];
    const float* Ws1 = (const float*)d_in[9];
    const float* bs1 = (const float*)d_in[10];
    const float* Ws2 = (const float*)d_in[11];
    const float* bs2 = (const float*)d_in[12];
    float* out = (float*)d_out;

    // flags: [TT][8][128] u32 = 2 MB (per-wave, per-t, never reused);
    // hbuf: [2][BB][HH] bf16 = 256 KB ping-pong (no zeroing needed: first
    // read is at t=1 of slot 0, fully written at t=0).
    unsigned int*   flags = (unsigned int*)d_ws;
    unsigned short* hbuf  = (unsigned short*)((char*)d_ws + (size_t)TT * 8 * 128 * 4);

    hipMemsetAsync(d_ws, 0, (size_t)TT * 8 * 128 * 4, stream);
    qlstm_kernel<<<dim3(256), dim3(256), 0, stream>>>(
        X, Wf, bfb, Wi, bi, Wu, bu, Wo, bo, Ws1, bs1, Ws2, bs2, out, flags, hbuf);
}